// Round 4
// baseline (129.933 us; speedup 1.0000x reference)
//
#include <hip/hip_runtime.h>
#include <hip/hip_bf16.h>
#include <cstdint>
#include <cstddef>

typedef __bf16 bf16x8 __attribute__((ext_vector_type(8)));
typedef __bf16 bf16x4 __attribute__((ext_vector_type(4)));
typedef float  f32x4  __attribute__((ext_vector_type(4)));

#define D_DIM 1024
#define BM 128
#define BN 128
#define BK 64
#define NXCD 8

#define GLB(p) ((const __attribute__((address_space(1))) void*)(p))
#define LDS(p) ((__attribute__((address_space(3))) void*)(p))

// ---- stage 0: convert x (fp32) -> padded bf16 (8 elems/thread), zero cnt ----
__global__ __launch_bounds__(256) void conv_x_kernel(
    const float* __restrict__ x, __bf16* __restrict__ xb,
    int* __restrict__ cnt, int N, int MP)
{
    int i = blockIdx.x * 256 + threadIdx.x;      // group of 8 elements
    if (i < N) cnt[i] = 0;                        // zero degree counters
    int total = MP * (D_DIM / 8);
    if (i >= total) return;
    int row = i >> 7;                             // D/8 = 128 groups per row
    size_t base = (size_t)i * 8;
    bf16x8 o;
    if (row < N) {
        float4 v0 = *(const float4*)(x + base);
        float4 v1 = *(const float4*)(x + base + 4);
        o[0] = (__bf16)v0.x; o[1] = (__bf16)v0.y; o[2] = (__bf16)v0.z; o[3] = (__bf16)v0.w;
        o[4] = (__bf16)v1.x; o[5] = (__bf16)v1.y; o[6] = (__bf16)v1.z; o[7] = (__bf16)v1.w;
    } else {
        #pragma unroll
        for (int j = 0; j < 8; ++j) o[j] = (__bf16)0.f;
    }
    *(bf16x8*)(xb + base) = o;
}

// ---- stage 0b: W [K][N] fp32 -> W^T [N][K] bf16 (tiled transpose) ----
__global__ void transpose_w_kernel(const float* __restrict__ W, __bf16* __restrict__ wT)
{
    __shared__ float tile[32][33];
    int nb = blockIdx.x * 32, kb = blockIdx.y * 32;
    int tx = threadIdx.x, ty = threadIdx.y;      // (32, 8)
    #pragma unroll
    for (int i = 0; i < 32; i += 8)
        tile[ty + i][tx] = W[(size_t)(kb + ty + i) * D_DIM + nb + tx];
    __syncthreads();
    #pragma unroll
    for (int i = 0; i < 32; i += 8)
        wT[(size_t)(nb + ty + i) * D_DIM + kb + tx] = (__bf16)tile[tx][ty + i];
}

// ---- stage 1: degree count over dst ----
__global__ __launch_bounds__(256) void count_kernel(
    const int* __restrict__ dst, int* __restrict__ cnt, int E)
{
    int e = blockIdx.x * 256 + threadIdx.x;
    if (e < E) atomicAdd(&cnt[dst[e]], 1);
}

// ---- stage 2: single-block scan (LDS-prefetched) -> row_ptr/cursor/dinv ----
__global__ __launch_bounds__(1024) void scan_kernel(
    const int* __restrict__ cnt, int* __restrict__ row_ptr,
    int* __restrict__ cursor, float* __restrict__ dinv, int N)
{
    __shared__ int sbuf[10240];                  // N <= 10240
    __shared__ int wsum[16];
    __shared__ int sctot;
    int tid = threadIdx.x, lane = tid & 63, wid = tid >> 6;
    int chunks = (N + 1023) >> 10;
    #pragma unroll 4
    for (int ch = 0; ch < chunks; ++ch) {
        int i = (ch << 10) + tid;
        sbuf[(ch << 10) + tid] = (i < N) ? cnt[i] : 0;
    }
    __syncthreads();
    int carry = 0;
    for (int ch = 0; ch < chunks; ++ch) {
        int i = (ch << 10) + tid;
        int c = sbuf[(ch << 10) + tid];
        int v = c;
        #pragma unroll
        for (int off = 1; off < 64; off <<= 1) {
            int t = __shfl_up(v, off);
            if (lane >= off) v += t;
        }
        if (lane == 63) wsum[wid] = v;
        __syncthreads();
        if (tid < 16) {
            int s = wsum[tid];
            int sv = s;
            #pragma unroll
            for (int off = 1; off < 16; off <<= 1) {
                int t = __shfl_up(sv, off);
                if (tid >= off) sv += t;
            }
            wsum[tid] = sv - s;                  // exclusive wave offset
            if (tid == 15) sctot = sv;
        }
        __syncthreads();
        int incl = carry + wsum[wid] + v;
        if (i < N) {
            int excl = incl - c;
            row_ptr[i] = excl;
            cursor[i]  = excl;
            dinv[i] = rsqrtf((float)c + 1.0f);   // +1 self loop, always > 0
        }
        carry += sctot;
        __syncthreads();
    }
    if (tid == 0) row_ptr[N] = carry;
}

// ---- stage 3: CSR fill ----
__global__ __launch_bounds__(256) void fill_kernel(
    const int* __restrict__ src, const int* __restrict__ dst,
    int* __restrict__ cursor, int* __restrict__ col, int E)
{
    int e = blockIdx.x * 256 + threadIdx.x;
    if (e < E) {
        int d = dst[e];
        int pos = atomicAdd(&cursor[d], 1);
        col[pos] = src[e];
    }
}

// ---- stage 4: h = xb @ W ----
// 128x128 tile, BK=64, XCD-chunked remap, 2-phase prefetch (double-buffered
// LDS, stage t+1 before compute t), T2 XOR-swizzle via inverse-swizzled
// GLOBAL source + linear LDS dest + swizzled ds_read.
__global__ __launch_bounds__(256) void gemm_kernel(
    const __bf16* __restrict__ A,   // [MP][K] bf16
    const __bf16* __restrict__ BT,  // [N][K] bf16 (W transposed)
    __bf16* __restrict__ C,         // [MP][N] bf16
    int K, int N, int mtiles, int ntiles, int chunk)
{
    __shared__ __bf16 As0[BM * BK], Bs0[BN * BK];
    __shared__ __bf16 As1[BM * BK], Bs1[BN * BK];

    int wg = blockIdx.x;
    int c8 = wg & (NXCD - 1);
    int r  = wg >> 3;
    int bm = c8 * chunk + r / ntiles;
    int bn = r % ntiles;
    if (bm >= mtiles) return;

    int tid = threadIdx.x;
    int wid = tid >> 6, lane = tid & 63;
    int wr = wid >> 1, wc = wid & 1;             // 2x2 wave grid, 64x64 each

    auto stage = [&](int ks, __bf16* dA, __bf16* dB) {
        #pragma unroll
        for (int i = 0; i < 4; ++i) {
            int c   = i * 256 + wid * 64 + lane; // 16B chunk id, lane-contiguous
            int row = c >> 3;                    // 8 chunks per 64-elem row
            int js  = (c & 7) ^ (row & 7);       // inverse-swizzled source chunk
            const __bf16* ga = A  + (size_t)(bm * BM + row) * K + ks * BK + js * 8;
            const __bf16* gb = BT + (size_t)(bn * BN + row) * K + ks * BK + js * 8;
            __builtin_amdgcn_global_load_lds(GLB(ga), LDS(dA + c * 8), 16, 0, 0);
            __builtin_amdgcn_global_load_lds(GLB(gb), LDS(dB + c * 8), 16, 0, 0);
        }
    };

    f32x4 acc[4][4] = {};
    const int ksteps = K / BK;

    __bf16 *rdA = As0, *rdB = Bs0, *wrA = As1, *wrB = Bs1;
    stage(0, rdA, rdB);
    asm volatile("s_waitcnt vmcnt(0)" ::: "memory");
    __syncthreads();

    for (int ks = 0; ks < ksteps; ++ks) {
        if (ks + 1 < ksteps) stage(ks + 1, wrA, wrB);   // prefetch next tile
        #pragma unroll
        for (int kk = 0; kk < 2; ++kk) {
            bf16x8 af[4], bfr[4];
            int jgrp = kk * 4 + (lane >> 4);             // chunk index 0..7
            #pragma unroll
            for (int mi = 0; mi < 4; ++mi) {
                int rr = wr * 64 + mi * 16 + (lane & 15);
                af[mi] = *(const bf16x8*)(rdA + rr * BK + ((jgrp ^ (rr & 7)) << 3));
            }
            #pragma unroll
            for (int ni = 0; ni < 4; ++ni) {
                int rr = wc * 64 + ni * 16 + (lane & 15);
                bfr[ni] = *(const bf16x8*)(rdB + rr * BK + ((jgrp ^ (rr & 7)) << 3));
            }
            #pragma unroll
            for (int mi = 0; mi < 4; ++mi)
                #pragma unroll
                for (int ni = 0; ni < 4; ++ni)
                    acc[mi][ni] = __builtin_amdgcn_mfma_f32_16x16x32_bf16(
                        af[mi], bfr[ni], acc[mi][ni], 0, 0, 0);
        }
        asm volatile("s_waitcnt vmcnt(0)" ::: "memory");  // prefetch landed
        __syncthreads();                                   // all waves done reading rd
        __bf16* t;
        t = rdA; rdA = wrA; wrA = t;
        t = rdB; rdB = wrB; wrB = t;
    }

    // C layout: col = lane&15, row = (lane>>4)*4 + r   [m89-verified]
    #pragma unroll
    for (int mi = 0; mi < 4; ++mi)
        #pragma unroll
        for (int ni = 0; ni < 4; ++ni)
            #pragma unroll
            for (int rr = 0; rr < 4; ++rr) {
                int row = bm * BM + wr * 64 + mi * 16 + (lane >> 4) * 4 + rr;
                int colc = bn * BN + wc * 64 + ni * 16 + (lane & 15);
                C[(size_t)row * N + colc] = (__bf16)acc[mi][ni][rr];
            }
}

// ---- stage 5: gather-accumulate + bias + ReLU ----
// 2 dst rows per 256-thread block; 128 lanes x bf16x8 (16B) per row.
// 8-deep DECOUPLED pipeline: batch 8 col loads -> 8 weight loads -> 8 row
// gathers (8KB/wave in flight) -> FMAs. Breaks the col->dinv->gather serial
// address chain that capped MLP. LDS remap for coalesced fp32 stores.
__global__ __launch_bounds__(256) void scatter_kernel(
    const __bf16* __restrict__ h, const int* __restrict__ row_ptr,
    const int* __restrict__ col, const float* __restrict__ dinv,
    const float* __restrict__ b, float* __restrict__ out, int N)
{
    __shared__ float obuf[2][D_DIM];
    int half = threadIdx.x >> 7;                 // row selector within block
    int t    = threadIdx.x & 127;
    int d    = blockIdx.x * 2 + half;
    int cbase = t * 8;

    if (d < N) {
        float dv = dinv[d];
        float acc[8];
        bf16x8 v = *(const bf16x8*)(h + (size_t)d * D_DIM + cbase);
        float sw = dv * dv;                      // self loop
        #pragma unroll
        for (int j = 0; j < 8; ++j) acc[j] = (float)v[j] * sw;

        int r0 = row_ptr[d], r1 = row_ptr[d + 1];
        int e = r0;
        while (e + 8 <= r1) {
            int s[8];
            #pragma unroll
            for (int q = 0; q < 8; ++q) s[q] = col[e + q];
            float w[8];
            #pragma unroll
            for (int q = 0; q < 8; ++q) w[q] = dinv[s[q]] * dv;
            bf16x8 u[8];
            #pragma unroll
            for (int q = 0; q < 8; ++q)
                u[q] = *(const bf16x8*)(h + (size_t)s[q] * D_DIM + cbase);
            #pragma unroll
            for (int q = 0; q < 8; ++q)
                #pragma unroll
                for (int j = 0; j < 8; ++j) acc[j] = fmaf((float)u[q][j], w[q], acc[j]);
            e += 8;
        }
        if (e + 4 <= r1) {
            int s[4];
            #pragma unroll
            for (int q = 0; q < 4; ++q) s[q] = col[e + q];
            float w[4];
            #pragma unroll
            for (int q = 0; q < 4; ++q) w[q] = dinv[s[q]] * dv;
            bf16x8 u[4];
            #pragma unroll
            for (int q = 0; q < 4; ++q)
                u[q] = *(const bf16x8*)(h + (size_t)s[q] * D_DIM + cbase);
            #pragma unroll
            for (int q = 0; q < 4; ++q)
                #pragma unroll
                for (int j = 0; j < 8; ++j) acc[j] = fmaf((float)u[q][j], w[q], acc[j]);
            e += 4;
        }
        for (; e < r1; ++e) {
            int s = col[e];
            float w = dinv[s] * dv;
            bf16x8 u = *(const bf16x8*)(h + (size_t)s * D_DIM + cbase);
            #pragma unroll
            for (int j = 0; j < 8; ++j) acc[j] = fmaf((float)u[j], w, acc[j]);
        }
        float4 b0 = *(const float4*)(b + cbase);
        float4 b1 = *(const float4*)(b + cbase + 4);
        obuf[half][cbase + 0] = fmaxf(acc[0] + b0.x, 0.f);
        obuf[half][cbase + 1] = fmaxf(acc[1] + b0.y, 0.f);
        obuf[half][cbase + 2] = fmaxf(acc[2] + b0.z, 0.f);
        obuf[half][cbase + 3] = fmaxf(acc[3] + b0.w, 0.f);
        obuf[half][cbase + 4] = fmaxf(acc[4] + b1.x, 0.f);
        obuf[half][cbase + 5] = fmaxf(acc[5] + b1.y, 0.f);
        obuf[half][cbase + 6] = fmaxf(acc[6] + b1.z, 0.f);
        obuf[half][cbase + 7] = fmaxf(acc[7] + b1.w, 0.f);
    }
    __syncthreads();
    int d0 = blockIdx.x * 2;
    #pragma unroll
    for (int rsel = 0; rsel < 2; ++rsel) {
        int dd = d0 + rsel;
        if (dd < N) {
            float4 vv = *(const float4*)&obuf[rsel][threadIdx.x * 4];
            *(float4*)(out + (size_t)dd * D_DIM + threadIdx.x * 4) = vv;
        }
    }
}

extern "C" void kernel_launch(void* const* d_in, const int* in_sizes, int n_in,
                              void* d_out, int out_size, void* d_ws, size_t ws_size,
                              hipStream_t stream)
{
    const float* x  = (const float*)d_in[0];
    const int*   ei = (const int*)d_in[1];
    const float* W  = (const float*)d_in[2];
    const float* b  = (const float*)d_in[3];
    float* out = (float*)d_out;

    const int N = in_sizes[0] / D_DIM;     // 10000
    const int E = in_sizes[1] / 2;         // 160000
    const int MP = ((N + BM - 1) / BM) * BM; // 10112
    const int K = D_DIM;

    const int* src = ei;
    const int* dst = ei + E;

    // ws bump allocator, 256B aligned
    char* ws = (char*)d_ws;
    size_t off = 0;
    auto alloc = [&](size_t bytes) -> char* {
        char* p = ws + off;
        off += (bytes + 255) & ~(size_t)255;
        return p;
    };
    __bf16* xb     = (__bf16*)alloc((size_t)MP * D_DIM * 2);
    __bf16* wT     = (__bf16*)alloc((size_t)D_DIM * D_DIM * 2);
    __bf16* h      = (__bf16*)alloc((size_t)MP * D_DIM * 2);
    int*    cnt    = (int*)alloc((size_t)N * 4);
    int*    rowptr = (int*)alloc((size_t)(N + 1) * 4);
    int*    cursor = (int*)alloc((size_t)N * 4);
    int*    colbuf = (int*)alloc((size_t)E * 4);
    float*  dinv   = (float*)alloc((size_t)N * 4);
    (void)ws_size;

    // 0: convert x -> padded bf16 (also zeroes cnt)
    int groups = MP * (D_DIM / 8);
    conv_x_kernel<<<(groups + 255) / 256, 256, 0, stream>>>(x, xb, cnt, N, MP);
    // 0b: W -> W^T bf16
    transpose_w_kernel<<<dim3(D_DIM / 32, D_DIM / 32), dim3(32, 8), 0, stream>>>(W, wT);
    // 1: degree count
    count_kernel<<<(E + 255) / 256, 256, 0, stream>>>(dst, cnt, E);
    // 2: scan -> row_ptr, cursor, dinv
    scan_kernel<<<1, 1024, 0, stream>>>(cnt, rowptr, cursor, dinv, N);
    // 3: CSR fill
    fill_kernel<<<(E + 255) / 256, 256, 0, stream>>>(src, dst, cursor, colbuf, E);
    // 4: h = xb @ W (bf16 MFMA) — XCD-chunked + 2-phase prefetch + swizzle
    int mtiles = MP / BM;                      // 79
    int ntiles = D_DIM / BN;                   // 8
    int chunk  = (mtiles + NXCD - 1) / NXCD;   // 10
    int nblocks = NXCD * chunk * ntiles;       // 640 (8 early-exit)
    gemm_kernel<<<nblocks, 256, 0, stream>>>(xb, wT, h, K, D_DIM, mtiles, ntiles, chunk);
    // 5: gather-accumulate + bias + relu
    scatter_kernel<<<(N + 1) / 2, 256, 0, stream>>>(h, rowptr, colbuf, dinv, b, out, N);
}

// Round 6
// 128.085 us; speedup vs baseline: 1.0144x; 1.0144x over previous
//
#include <hip/hip_runtime.h>
#include <hip/hip_bf16.h>
#include <cstdint>
#include <cstddef>

typedef __bf16 bf16x8 __attribute__((ext_vector_type(8)));
typedef __bf16 bf16x4 __attribute__((ext_vector_type(4)));
typedef float  f32x4  __attribute__((ext_vector_type(4)));

#define D_DIM 1024
#define BM 128
#define BN 128
#define BK 64
#define NXCD 8

#define GLB(p) ((const __attribute__((address_space(1))) void*)(p))
#define LDS(p) ((__attribute__((address_space(3))) void*)(p))

// ---- stage 0: convert x (fp32) -> padded bf16 (8 elems/thread), zero cnt ----
__global__ __launch_bounds__(256) void conv_x_kernel(
    const float* __restrict__ x, __bf16* __restrict__ xb,
    int* __restrict__ cnt, int N, int MP)
{
    int i = blockIdx.x * 256 + threadIdx.x;      // group of 8 elements
    if (i < N) cnt[i] = 0;                        // zero degree counters
    int total = MP * (D_DIM / 8);
    if (i >= total) return;
    int row = i >> 7;                             // D/8 = 128 groups per row
    size_t base = (size_t)i * 8;
    bf16x8 o;
    if (row < N) {
        float4 v0 = *(const float4*)(x + base);
        float4 v1 = *(const float4*)(x + base + 4);
        o[0] = (__bf16)v0.x; o[1] = (__bf16)v0.y; o[2] = (__bf16)v0.z; o[3] = (__bf16)v0.w;
        o[4] = (__bf16)v1.x; o[5] = (__bf16)v1.y; o[6] = (__bf16)v1.z; o[7] = (__bf16)v1.w;
    } else {
        #pragma unroll
        for (int j = 0; j < 8; ++j) o[j] = (__bf16)0.f;
    }
    *(bf16x8*)(xb + base) = o;
}

// ---- stage 0b: W [K][N] fp32 -> W^T [N][K] bf16 (tiled transpose) ----
__global__ void transpose_w_kernel(const float* __restrict__ W, __bf16* __restrict__ wT)
{
    __shared__ float tile[32][33];
    int nb = blockIdx.x * 32, kb = blockIdx.y * 32;
    int tx = threadIdx.x, ty = threadIdx.y;      // (32, 8)
    #pragma unroll
    for (int i = 0; i < 32; i += 8)
        tile[ty + i][tx] = W[(size_t)(kb + ty + i) * D_DIM + nb + tx];
    __syncthreads();
    #pragma unroll
    for (int i = 0; i < 32; i += 8)
        wT[(size_t)(nb + ty + i) * D_DIM + kb + tx] = (__bf16)tile[tx][ty + i];
}

// ---- stage 1: degree count over dst ----
__global__ __launch_bounds__(256) void count_kernel(
    const int* __restrict__ dst, int* __restrict__ cnt, int E)
{
    int e = blockIdx.x * 256 + threadIdx.x;
    if (e < E) atomicAdd(&cnt[dst[e]], 1);
}

// ---- stage 2: single-block scan (LDS-prefetched) -> row_ptr/cursor/dinv ----
__global__ __launch_bounds__(1024) void scan_kernel(
    const int* __restrict__ cnt, int* __restrict__ row_ptr,
    int* __restrict__ cursor, float* __restrict__ dinv, int N)
{
    __shared__ int sbuf[10240];                  // N <= 10240
    __shared__ int wsum[16];
    __shared__ int sctot;
    int tid = threadIdx.x, lane = tid & 63, wid = tid >> 6;
    int chunks = (N + 1023) >> 10;
    #pragma unroll 4
    for (int ch = 0; ch < chunks; ++ch) {
        int i = (ch << 10) + tid;
        sbuf[(ch << 10) + tid] = (i < N) ? cnt[i] : 0;
    }
    __syncthreads();
    int carry = 0;
    for (int ch = 0; ch < chunks; ++ch) {
        int i = (ch << 10) + tid;
        int c = sbuf[(ch << 10) + tid];
        int v = c;
        #pragma unroll
        for (int off = 1; off < 64; off <<= 1) {
            int t = __shfl_up(v, off);
            if (lane >= off) v += t;
        }
        if (lane == 63) wsum[wid] = v;
        __syncthreads();
        if (tid < 16) {
            int s = wsum[tid];
            int sv = s;
            #pragma unroll
            for (int off = 1; off < 16; off <<= 1) {
                int t = __shfl_up(sv, off);
                if (tid >= off) sv += t;
            }
            wsum[tid] = sv - s;                  // exclusive wave offset
            if (tid == 15) sctot = sv;
        }
        __syncthreads();
        int incl = carry + wsum[wid] + v;
        if (i < N) {
            int excl = incl - c;
            row_ptr[i] = excl;
            cursor[i]  = excl;
            dinv[i] = rsqrtf((float)c + 1.0f);   // +1 self loop, always > 0
        }
        carry += sctot;
        __syncthreads();
    }
    if (tid == 0) row_ptr[N] = carry;
}

// ---- stage 3: CSR fill ----
__global__ __launch_bounds__(256) void fill_kernel(
    const int* __restrict__ src, const int* __restrict__ dst,
    int* __restrict__ cursor, int* __restrict__ col, int E)
{
    int e = blockIdx.x * 256 + threadIdx.x;
    if (e < E) {
        int d = dst[e];
        int pos = atomicAdd(&cursor[d], 1);
        col[pos] = src[e];
    }
}

// ---- stage 4: h = xb @ W ----
// 128x128 tile, BK=64, XCD-chunked remap, 2-phase prefetch (double-buffered
// LDS, stage t+1 before compute t), T2 XOR-swizzle via inverse-swizzled
// GLOBAL source + linear LDS dest + swizzled ds_read.
__global__ __launch_bounds__(256) void gemm_kernel(
    const __bf16* __restrict__ A,   // [MP][K] bf16
    const __bf16* __restrict__ BT,  // [N][K] bf16 (W transposed)
    __bf16* __restrict__ C,         // [MP][N] bf16
    int K, int N, int mtiles, int ntiles, int chunk)
{
    __shared__ __bf16 As0[BM * BK], Bs0[BN * BK];
    __shared__ __bf16 As1[BM * BK], Bs1[BN * BK];

    int wg = blockIdx.x;
    int c8 = wg & (NXCD - 1);
    int r  = wg >> 3;
    int bm = c8 * chunk + r / ntiles;
    int bn = r % ntiles;
    if (bm >= mtiles) return;

    int tid = threadIdx.x;
    int wid = tid >> 6, lane = tid & 63;
    int wr = wid >> 1, wc = wid & 1;             // 2x2 wave grid, 64x64 each

    auto stage = [&](int ks, __bf16* dA, __bf16* dB) {
        #pragma unroll
        for (int i = 0; i < 4; ++i) {
            int c   = i * 256 + wid * 64 + lane; // 16B chunk id, lane-contiguous
            int row = c >> 3;                    // 8 chunks per 64-elem row
            int js  = (c & 7) ^ (row & 7);       // inverse-swizzled source chunk
            const __bf16* ga = A  + (size_t)(bm * BM + row) * K + ks * BK + js * 8;
            const __bf16* gb = BT + (size_t)(bn * BN + row) * K + ks * BK + js * 8;
            __builtin_amdgcn_global_load_lds(GLB(ga), LDS(dA + c * 8), 16, 0, 0);
            __builtin_amdgcn_global_load_lds(GLB(gb), LDS(dB + c * 8), 16, 0, 0);
        }
    };

    f32x4 acc[4][4] = {};
    const int ksteps = K / BK;

    __bf16 *rdA = As0, *rdB = Bs0, *wrA = As1, *wrB = Bs1;
    stage(0, rdA, rdB);
    asm volatile("s_waitcnt vmcnt(0)" ::: "memory");
    __syncthreads();

    for (int ks = 0; ks < ksteps; ++ks) {
        if (ks + 1 < ksteps) stage(ks + 1, wrA, wrB);   // prefetch next tile
        #pragma unroll
        for (int kk = 0; kk < 2; ++kk) {
            bf16x8 af[4], bfr[4];
            int jgrp = kk * 4 + (lane >> 4);             // chunk index 0..7
            #pragma unroll
            for (int mi = 0; mi < 4; ++mi) {
                int rr = wr * 64 + mi * 16 + (lane & 15);
                af[mi] = *(const bf16x8*)(rdA + rr * BK + ((jgrp ^ (rr & 7)) << 3));
            }
            #pragma unroll
            for (int ni = 0; ni < 4; ++ni) {
                int rr = wc * 64 + ni * 16 + (lane & 15);
                bfr[ni] = *(const bf16x8*)(rdB + rr * BK + ((jgrp ^ (rr & 7)) << 3));
            }
            #pragma unroll
            for (int mi = 0; mi < 4; ++mi)
                #pragma unroll
                for (int ni = 0; ni < 4; ++ni)
                    acc[mi][ni] = __builtin_amdgcn_mfma_f32_16x16x32_bf16(
                        af[mi], bfr[ni], acc[mi][ni], 0, 0, 0);
        }
        asm volatile("s_waitcnt vmcnt(0)" ::: "memory");  // prefetch landed
        __syncthreads();                                   // all waves done reading rd
        __bf16* t;
        t = rdA; rdA = wrA; wrA = t;
        t = rdB; rdB = wrB; wrB = t;
    }

    // C layout: col = lane&15, row = (lane>>4)*4 + r   [m89-verified]
    #pragma unroll
    for (int mi = 0; mi < 4; ++mi)
        #pragma unroll
        for (int ni = 0; ni < 4; ++ni)
            #pragma unroll
            for (int rr = 0; rr < 4; ++rr) {
                int row = bm * BM + wr * 64 + mi * 16 + (lane >> 4) * 4 + rr;
                int colc = bn * BN + wc * 64 + ni * 16 + (lane & 15);
                C[(size_t)row * N + colc] = (__bf16)acc[mi][ni][rr];
            }
}

// ---- stage 5: gather-accumulate + bias + ReLU, D-SPLIT ----
// One wave per dst row, 64 lanes x bf16x8 = 512 columns per pass.
// Two sequential launches (dlo = 0, 512) halve the gather working set
// (20.7 -> 10.3 MB) to raise per-XCD L2 hit rate. Nontemporal output
// stores keep the 41 MB out-stream from evicting h lines.
__global__ __launch_bounds__(256) void scatter_kernel(
    const __bf16* __restrict__ h, const int* __restrict__ row_ptr,
    const int* __restrict__ col, const float* __restrict__ dinv,
    const float* __restrict__ b, float* __restrict__ out, int N, int dlo)
{
    int wid  = threadIdx.x >> 6;
    int lane = threadIdx.x & 63;
    int d = blockIdx.x * 4 + wid;
    if (d >= N) return;
    int cbase = dlo + lane * 8;
    const __bf16* hp = h + cbase;

    float dv = dinv[d];
    float acc[8];
    bf16x8 v = *(const bf16x8*)(hp + (size_t)d * D_DIM);
    float sw = dv * dv;                          // self loop
    #pragma unroll
    for (int j = 0; j < 8; ++j) acc[j] = (float)v[j] * sw;

    int r0 = row_ptr[d], r1 = row_ptr[d + 1];
    int e = r0;
    while (e + 8 <= r1) {
        int s[8];
        #pragma unroll
        for (int q = 0; q < 8; ++q) s[q] = col[e + q];
        float w[8];
        #pragma unroll
        for (int q = 0; q < 8; ++q) w[q] = dinv[s[q]] * dv;
        bf16x8 u[8];
        #pragma unroll
        for (int q = 0; q < 8; ++q)
            u[q] = *(const bf16x8*)(hp + (size_t)s[q] * D_DIM);
        #pragma unroll
        for (int q = 0; q < 8; ++q)
            #pragma unroll
            for (int j = 0; j < 8; ++j) acc[j] = fmaf((float)u[q][j], w[q], acc[j]);
        e += 8;
    }
    if (e + 4 <= r1) {
        int s[4];
        #pragma unroll
        for (int q = 0; q < 4; ++q) s[q] = col[e + q];
        float w[4];
        #pragma unroll
        for (int q = 0; q < 4; ++q) w[q] = dinv[s[q]] * dv;
        bf16x8 u[4];
        #pragma unroll
        for (int q = 0; q < 4; ++q)
            u[q] = *(const bf16x8*)(hp + (size_t)s[q] * D_DIM);
        #pragma unroll
        for (int q = 0; q < 4; ++q)
            #pragma unroll
            for (int j = 0; j < 8; ++j) acc[j] = fmaf((float)u[q][j], w[q], acc[j]);
        e += 4;
    }
    for (; e < r1; ++e) {
        int s = col[e];
        float w = dinv[s] * dv;
        bf16x8 u = *(const bf16x8*)(hp + (size_t)s * D_DIM);
        #pragma unroll
        for (int j = 0; j < 8; ++j) acc[j] = fmaf((float)u[j], w, acc[j]);
    }

    float4 b0 = *(const float4*)(b + cbase);
    float4 b1 = *(const float4*)(b + cbase + 4);
    f32x4 o0, o1;
    o0[0] = fmaxf(acc[0] + b0.x, 0.f);
    o0[1] = fmaxf(acc[1] + b0.y, 0.f);
    o0[2] = fmaxf(acc[2] + b0.z, 0.f);
    o0[3] = fmaxf(acc[3] + b0.w, 0.f);
    o1[0] = fmaxf(acc[4] + b1.x, 0.f);
    o1[1] = fmaxf(acc[5] + b1.y, 0.f);
    o1[2] = fmaxf(acc[6] + b1.z, 0.f);
    o1[3] = fmaxf(acc[7] + b1.w, 0.f);
    float* op = out + (size_t)d * D_DIM + cbase;
    __builtin_nontemporal_store(o0, (f32x4*)op);
    __builtin_nontemporal_store(o1, (f32x4*)(op + 4));
}

extern "C" void kernel_launch(void* const* d_in, const int* in_sizes, int n_in,
                              void* d_out, int out_size, void* d_ws, size_t ws_size,
                              hipStream_t stream)
{
    const float* x  = (const float*)d_in[0];
    const int*   ei = (const int*)d_in[1];
    const float* W  = (const float*)d_in[2];
    const float* b  = (const float*)d_in[3];
    float* out = (float*)d_out;

    const int N = in_sizes[0] / D_DIM;     // 10000
    const int E = in_sizes[1] / 2;         // 160000
    const int MP = ((N + BM - 1) / BM) * BM; // 10112
    const int K = D_DIM;

    const int* src = ei;
    const int* dst = ei + E;

    // ws bump allocator, 256B aligned
    char* ws = (char*)d_ws;
    size_t off = 0;
    auto alloc = [&](size_t bytes) -> char* {
        char* p = ws + off;
        off += (bytes + 255) & ~(size_t)255;
        return p;
    };
    __bf16* xb     = (__bf16*)alloc((size_t)MP * D_DIM * 2);
    __bf16* wT     = (__bf16*)alloc((size_t)D_DIM * D_DIM * 2);
    __bf16* h      = (__bf16*)alloc((size_t)MP * D_DIM * 2);
    int*    cnt    = (int*)alloc((size_t)N * 4);
    int*    rowptr = (int*)alloc((size_t)(N + 1) * 4);
    int*    cursor = (int*)alloc((size_t)N * 4);
    int*    colbuf = (int*)alloc((size_t)E * 4);
    float*  dinv   = (float*)alloc((size_t)N * 4);
    (void)ws_size;

    // 0: convert x -> padded bf16 (also zeroes cnt)
    int groups = MP * (D_DIM / 8);
    conv_x_kernel<<<(groups + 255) / 256, 256, 0, stream>>>(x, xb, cnt, N, MP);
    // 0b: W -> W^T bf16
    transpose_w_kernel<<<dim3(D_DIM / 32, D_DIM / 32), dim3(32, 8), 0, stream>>>(W, wT);
    // 1: degree count
    count_kernel<<<(E + 255) / 256, 256, 0, stream>>>(dst, cnt, E);
    // 2: scan -> row_ptr, cursor, dinv
    scan_kernel<<<1, 1024, 0, stream>>>(cnt, rowptr, cursor, dinv, N);
    // 3: CSR fill
    fill_kernel<<<(E + 255) / 256, 256, 0, stream>>>(src, dst, cursor, colbuf, E);
    // 4: h = xb @ W (bf16 MFMA) — XCD-chunked + 2-phase prefetch + swizzle
    int mtiles = MP / BM;                      // 79
    int ntiles = D_DIM / BN;                   // 8
    int chunk  = (mtiles + NXCD - 1) / NXCD;   // 10
    int nblocks = NXCD * chunk * ntiles;       // 640 (8 early-exit)
    gemm_kernel<<<nblocks, 256, 0, stream>>>(xb, wT, h, K, D_DIM, mtiles, ntiles, chunk);
    // 5: gather-accumulate + bias + relu — two D-half passes (L2 working set)
    scatter_kernel<<<(N + 3) / 4, 256, 0, stream>>>(h, rowptr, colbuf, dinv, b, out, N, 0);
    scatter_kernel<<<(N + 3) / 4, 256, 0, stream>>>(h, rowptr, colbuf, dinv, b, out, N, 512);
}

// Round 7
// 125.486 us; speedup vs baseline: 1.0354x; 1.0207x over previous
//
#include <hip/hip_runtime.h>
#include <hip/hip_bf16.h>
#include <cstdint>
#include <cstddef>

typedef __bf16 bf16x8 __attribute__((ext_vector_type(8)));
typedef __bf16 bf16x4 __attribute__((ext_vector_type(4)));
typedef float  f32x4  __attribute__((ext_vector_type(4)));
typedef float  f32x2  __attribute__((ext_vector_type(2)));

#define D_DIM 1024
#define BM 128
#define BN 128
#define BK 64
#define NXCD 8

#define GLB(p) ((const __attribute__((address_space(1))) void*)(p))
#define LDS(p) ((__attribute__((address_space(3))) void*)(p))

// ---- stage 0: convert x (fp32) -> padded bf16 (8 elems/thread), zero cnt ----
__global__ __launch_bounds__(256) void conv_x_kernel(
    const float* __restrict__ x, __bf16* __restrict__ xb,
    int* __restrict__ cnt, int N, int MP)
{
    int i = blockIdx.x * 256 + threadIdx.x;      // group of 8 elements
    if (i < N) cnt[i] = 0;                        // zero degree counters
    int total = MP * (D_DIM / 8);
    if (i >= total) return;
    int row = i >> 7;                             // D/8 = 128 groups per row
    size_t base = (size_t)i * 8;
    bf16x8 o;
    if (row < N) {
        float4 v0 = *(const float4*)(x + base);
        float4 v1 = *(const float4*)(x + base + 4);
        o[0] = (__bf16)v0.x; o[1] = (__bf16)v0.y; o[2] = (__bf16)v0.z; o[3] = (__bf16)v0.w;
        o[4] = (__bf16)v1.x; o[5] = (__bf16)v1.y; o[6] = (__bf16)v1.z; o[7] = (__bf16)v1.w;
    } else {
        #pragma unroll
        for (int j = 0; j < 8; ++j) o[j] = (__bf16)0.f;
    }
    *(bf16x8*)(xb + base) = o;
}

// ---- stage 0b: W [K][N] fp32 -> W^T [N][K] bf16 (tiled transpose) ----
__global__ void transpose_w_kernel(const float* __restrict__ W, __bf16* __restrict__ wT)
{
    __shared__ float tile[32][33];
    int nb = blockIdx.x * 32, kb = blockIdx.y * 32;
    int tx = threadIdx.x, ty = threadIdx.y;      // (32, 8)
    #pragma unroll
    for (int i = 0; i < 32; i += 8)
        tile[ty + i][tx] = W[(size_t)(kb + ty + i) * D_DIM + nb + tx];
    __syncthreads();
    #pragma unroll
    for (int i = 0; i < 32; i += 8)
        wT[(size_t)(nb + ty + i) * D_DIM + kb + tx] = (__bf16)tile[tx][ty + i];
}

// ---- stage 1: degree count over dst ----
__global__ __launch_bounds__(256) void count_kernel(
    const int* __restrict__ dst, int* __restrict__ cnt, int E)
{
    int e = blockIdx.x * 256 + threadIdx.x;
    if (e < E) atomicAdd(&cnt[dst[e]], 1);
}

// ---- stage 2: single-block scan (LDS-prefetched) -> row_ptr/cursor/dinv ----
__global__ __launch_bounds__(1024) void scan_kernel(
    const int* __restrict__ cnt, int* __restrict__ row_ptr,
    int* __restrict__ cursor, float* __restrict__ dinv, int N)
{
    __shared__ int sbuf[10240];                  // N <= 10240
    __shared__ int wsum[16];
    __shared__ int sctot;
    int tid = threadIdx.x, lane = tid & 63, wid = tid >> 6;
    int chunks = (N + 1023) >> 10;
    #pragma unroll 4
    for (int ch = 0; ch < chunks; ++ch) {
        int i = (ch << 10) + tid;
        sbuf[(ch << 10) + tid] = (i < N) ? cnt[i] : 0;
    }
    __syncthreads();
    int carry = 0;
    for (int ch = 0; ch < chunks; ++ch) {
        int i = (ch << 10) + tid;
        int c = sbuf[(ch << 10) + tid];
        int v = c;
        #pragma unroll
        for (int off = 1; off < 64; off <<= 1) {
            int t = __shfl_up(v, off);
            if (lane >= off) v += t;
        }
        if (lane == 63) wsum[wid] = v;
        __syncthreads();
        if (tid < 16) {
            int s = wsum[tid];
            int sv = s;
            #pragma unroll
            for (int off = 1; off < 16; off <<= 1) {
                int t = __shfl_up(sv, off);
                if (tid >= off) sv += t;
            }
            wsum[tid] = sv - s;                  // exclusive wave offset
            if (tid == 15) sctot = sv;
        }
        __syncthreads();
        int incl = carry + wsum[wid] + v;
        if (i < N) {
            int excl = incl - c;
            row_ptr[i] = excl;
            cursor[i]  = excl;
            dinv[i] = rsqrtf((float)c + 1.0f);   // +1 self loop, always > 0
        }
        carry += sctot;
        __syncthreads();
    }
    if (tid == 0) row_ptr[N] = carry;
}

// ---- stage 3: CSR fill ----
__global__ __launch_bounds__(256) void fill_kernel(
    const int* __restrict__ src, const int* __restrict__ dst,
    int* __restrict__ cursor, int* __restrict__ col, int E)
{
    int e = blockIdx.x * 256 + threadIdx.x;
    if (e < E) {
        int d = dst[e];
        int pos = atomicAdd(&cursor[d], 1);
        col[pos] = src[e];
    }
}

// ---- stage 4: h' = (xb @ W) * dinv[row]  (pre-scaled by src norm) ----
// 128x128 tile, BK=64, XCD-chunked remap, 2-phase prefetch (double-buffered
// LDS, stage t+1 before compute t), T2 XOR-swizzle via inverse-swizzled
// GLOBAL source + linear LDS dest + swizzled ds_read.
__global__ __launch_bounds__(256) void gemm_kernel(
    const __bf16* __restrict__ A,   // [MP][K] bf16
    const __bf16* __restrict__ BT,  // [N][K] bf16 (W transposed)
    __bf16* __restrict__ C,         // [MP][N] bf16 (pre-scaled h')
    const float* __restrict__ dinv, int Nn,
    int K, int N, int mtiles, int ntiles, int chunk)
{
    __shared__ __bf16 As0[BM * BK], Bs0[BN * BK];
    __shared__ __bf16 As1[BM * BK], Bs1[BN * BK];

    int wg = blockIdx.x;
    int c8 = wg & (NXCD - 1);
    int r  = wg >> 3;
    int bm = c8 * chunk + r / ntiles;
    int bn = r % ntiles;
    if (bm >= mtiles) return;

    int tid = threadIdx.x;
    int wid = tid >> 6, lane = tid & 63;
    int wr = wid >> 1, wc = wid & 1;             // 2x2 wave grid, 64x64 each

    auto stage = [&](int ks, __bf16* dA, __bf16* dB) {
        #pragma unroll
        for (int i = 0; i < 4; ++i) {
            int c   = i * 256 + wid * 64 + lane; // 16B chunk id, lane-contiguous
            int row = c >> 3;                    // 8 chunks per 64-elem row
            int js  = (c & 7) ^ (row & 7);       // inverse-swizzled source chunk
            const __bf16* ga = A  + (size_t)(bm * BM + row) * K + ks * BK + js * 8;
            const __bf16* gb = BT + (size_t)(bn * BN + row) * K + ks * BK + js * 8;
            __builtin_amdgcn_global_load_lds(GLB(ga), LDS(dA + c * 8), 16, 0, 0);
            __builtin_amdgcn_global_load_lds(GLB(gb), LDS(dB + c * 8), 16, 0, 0);
        }
    };

    f32x4 acc[4][4] = {};
    const int ksteps = K / BK;

    __bf16 *rdA = As0, *rdB = Bs0, *wrA = As1, *wrB = Bs1;
    stage(0, rdA, rdB);
    asm volatile("s_waitcnt vmcnt(0)" ::: "memory");
    __syncthreads();

    for (int ks = 0; ks < ksteps; ++ks) {
        if (ks + 1 < ksteps) stage(ks + 1, wrA, wrB);   // prefetch next tile
        #pragma unroll
        for (int kk = 0; kk < 2; ++kk) {
            bf16x8 af[4], bfr[4];
            int jgrp = kk * 4 + (lane >> 4);             // chunk index 0..7
            #pragma unroll
            for (int mi = 0; mi < 4; ++mi) {
                int rr = wr * 64 + mi * 16 + (lane & 15);
                af[mi] = *(const bf16x8*)(rdA + rr * BK + ((jgrp ^ (rr & 7)) << 3));
            }
            #pragma unroll
            for (int ni = 0; ni < 4; ++ni) {
                int rr = wc * 64 + ni * 16 + (lane & 15);
                bfr[ni] = *(const bf16x8*)(rdB + rr * BK + ((jgrp ^ (rr & 7)) << 3));
            }
            #pragma unroll
            for (int mi = 0; mi < 4; ++mi)
                #pragma unroll
                for (int ni = 0; ni < 4; ++ni)
                    acc[mi][ni] = __builtin_amdgcn_mfma_f32_16x16x32_bf16(
                        af[mi], bfr[ni], acc[mi][ni], 0, 0, 0);
        }
        asm volatile("s_waitcnt vmcnt(0)" ::: "memory");  // prefetch landed
        __syncthreads();                                   // all waves done reading rd
        __bf16* t;
        t = rdA; rdA = wrA; wrA = t;
        t = rdB; rdB = wrB; wrB = t;
    }

    // C layout: col = lane&15, row = (lane>>4)*4 + r   [m89-verified]
    // Pre-scale by dinv[row]: h'[r] = h[r] * dinv[r]  (src-side GCN norm)
    #pragma unroll
    for (int mi = 0; mi < 4; ++mi)
        #pragma unroll
        for (int rr = 0; rr < 4; ++rr) {
            int row = bm * BM + wr * 64 + mi * 16 + (lane >> 4) * 4 + rr;
            float dvr = (row < Nn) ? dinv[row] : 0.0f;
            #pragma unroll
            for (int ni = 0; ni < 4; ++ni) {
                int colc = bn * BN + wc * 64 + ni * 16 + (lane & 15);
                C[(size_t)row * N + colc] = (__bf16)(acc[mi][ni][rr] * dvr);
            }
        }
}

// ---- stage 5: gather-accumulate + bias + ReLU, XCD-COLUMN-SLICED ----
// Column chunk c = blockIdx%8 -> XCD c (round-robin dispatch). Each XCD
// only ever touches h'[:, 128c:128c+128] = 2.6 MB < 4 MB L2, killing the
// 8x per-XCD cold-miss replication (142 MB -> ~21 MB compulsory).
// h' is pre-scaled by dinv[src] in the GEMM epilogue, so the inner loop
// is a pure add; final out = dinv[d]*sum + b, ReLU, nontemporal store.
__global__ __launch_bounds__(256) void scatter_kernel(
    const __bf16* __restrict__ h, const int* __restrict__ row_ptr,
    const int* __restrict__ col, const float* __restrict__ dinv,
    const float* __restrict__ b, float* __restrict__ out, int N)
{
    int blk = blockIdx.x;
    int c   = blk & (NXCD - 1);                  // column chunk -> XCD
    int q   = blk >> 3;
    int wid = threadIdx.x >> 6, lane = threadIdx.x & 63;
    int d = q * 4 + wid;
    if (d >= N) return;
    int cbase = c * 128 + lane * 2;              // 2 bf16 cols per lane
    const __bf16* hp = h + cbase;

    // self loop term (h' already has dinv[d] folded in)
    uint32_t su = *(const uint32_t*)(hp + (size_t)d * D_DIM);
    float a0 = __uint_as_float(su << 16);
    float a1 = __uint_as_float(su & 0xffff0000u);

    int r0 = row_ptr[d], r1 = row_ptr[d + 1];
    int e = r0;
    while (e + 8 <= r1) {
        int s[8];
        #pragma unroll
        for (int t = 0; t < 8; ++t) s[t] = col[e + t];
        uint32_t u[8];
        #pragma unroll
        for (int t = 0; t < 8; ++t)
            u[t] = *(const uint32_t*)(hp + (size_t)s[t] * D_DIM);
        #pragma unroll
        for (int t = 0; t < 8; ++t) {
            a0 += __uint_as_float(u[t] << 16);
            a1 += __uint_as_float(u[t] & 0xffff0000u);
        }
        e += 8;
    }
    for (; e < r1; ++e) {
        uint32_t u = *(const uint32_t*)(hp + (size_t)col[e] * D_DIM);
        a0 += __uint_as_float(u << 16);
        a1 += __uint_as_float(u & 0xffff0000u);
    }

    float dv = dinv[d];
    f32x2 bb = *(const f32x2*)(b + cbase);
    f32x2 o;
    o[0] = fmaxf(fmaf(a0, dv, bb[0]), 0.f);
    o[1] = fmaxf(fmaf(a1, dv, bb[1]), 0.f);
    __builtin_nontemporal_store(o, (f32x2*)(out + (size_t)d * D_DIM + cbase));
}

extern "C" void kernel_launch(void* const* d_in, const int* in_sizes, int n_in,
                              void* d_out, int out_size, void* d_ws, size_t ws_size,
                              hipStream_t stream)
{
    const float* x  = (const float*)d_in[0];
    const int*   ei = (const int*)d_in[1];
    const float* W  = (const float*)d_in[2];
    const float* b  = (const float*)d_in[3];
    float* out = (float*)d_out;

    const int N = in_sizes[0] / D_DIM;     // 10000
    const int E = in_sizes[1] / 2;         // 160000
    const int MP = ((N + BM - 1) / BM) * BM; // 10112
    const int K = D_DIM;

    const int* src = ei;
    const int* dst = ei + E;

    // ws bump allocator, 256B aligned
    char* ws = (char*)d_ws;
    size_t off = 0;
    auto alloc = [&](size_t bytes) -> char* {
        char* p = ws + off;
        off += (bytes + 255) & ~(size_t)255;
        return p;
    };
    __bf16* xb     = (__bf16*)alloc((size_t)MP * D_DIM * 2);
    __bf16* wT     = (__bf16*)alloc((size_t)D_DIM * D_DIM * 2);
    __bf16* h      = (__bf16*)alloc((size_t)MP * D_DIM * 2);
    int*    cnt    = (int*)alloc((size_t)N * 4);
    int*    rowptr = (int*)alloc((size_t)(N + 1) * 4);
    int*    cursor = (int*)alloc((size_t)N * 4);
    int*    colbuf = (int*)alloc((size_t)E * 4);
    float*  dinv   = (float*)alloc((size_t)N * 4);
    (void)ws_size;

    // 0: convert x -> padded bf16 (also zeroes cnt)
    int groups = MP * (D_DIM / 8);
    conv_x_kernel<<<(groups + 255) / 256, 256, 0, stream>>>(x, xb, cnt, N, MP);
    // 0b: W -> W^T bf16
    transpose_w_kernel<<<dim3(D_DIM / 32, D_DIM / 32), dim3(32, 8), 0, stream>>>(W, wT);
    // 1: degree count
    count_kernel<<<(E + 255) / 256, 256, 0, stream>>>(dst, cnt, E);
    // 2: scan -> row_ptr, cursor, dinv
    scan_kernel<<<1, 1024, 0, stream>>>(cnt, rowptr, cursor, dinv, N);
    // 3: CSR fill
    fill_kernel<<<(E + 255) / 256, 256, 0, stream>>>(src, dst, cursor, colbuf, E);
    // 4: h' = (xb @ W) * dinv — XCD-chunked + 2-phase prefetch + swizzle
    int mtiles = MP / BM;                      // 79
    int ntiles = D_DIM / BN;                   // 8
    int chunk  = (mtiles + NXCD - 1) / NXCD;   // 10
    int nblocks = NXCD * chunk * ntiles;       // 640 (8 early-exit)
    gemm_kernel<<<nblocks, 256, 0, stream>>>(xb, wT, h, dinv, N, K, D_DIM,
                                             mtiles, ntiles, chunk);
    // 5: gather-accumulate + bias + relu — XCD column-sliced
    int sblocks = ((N + 3) / 4) * NXCD;        // 20000
    scatter_kernel<<<sblocks, 256, 0, stream>>>(h, rowptr, colbuf, dinv, b, out, N);
}

// Round 8
// 120.485 us; speedup vs baseline: 1.0784x; 1.0415x over previous
//
#include <hip/hip_runtime.h>
#include <hip/hip_bf16.h>
#include <cstdint>
#include <cstddef>

typedef __bf16 bf16x8 __attribute__((ext_vector_type(8)));
typedef __bf16 bf16x4 __attribute__((ext_vector_type(4)));
typedef float  f32x4  __attribute__((ext_vector_type(4)));
typedef float  f32x2  __attribute__((ext_vector_type(2)));

#define D_DIM 1024
#define BM 128
#define BN 128
#define BK 64
#define NXCD 8

#define GLB(p) ((const __attribute__((address_space(1))) void*)(p))
#define LDS(p) ((__attribute__((address_space(3))) void*)(p))

// ---- stage 0: convert x (fp32) -> padded bf16 (8 elems/thread), zero cnt ----
__global__ __launch_bounds__(256) void conv_x_kernel(
    const float* __restrict__ x, __bf16* __restrict__ xb,
    int* __restrict__ cnt, int N, int MP)
{
    int i = blockIdx.x * 256 + threadIdx.x;      // group of 8 elements
    if (i < N) cnt[i] = 0;                        // zero degree counters
    int total = MP * (D_DIM / 8);
    if (i >= total) return;
    int row = i >> 7;                             // D/8 = 128 groups per row
    size_t base = (size_t)i * 8;
    bf16x8 o;
    if (row < N) {
        float4 v0 = *(const float4*)(x + base);
        float4 v1 = *(const float4*)(x + base + 4);
        o[0] = (__bf16)v0.x; o[1] = (__bf16)v0.y; o[2] = (__bf16)v0.z; o[3] = (__bf16)v0.w;
        o[4] = (__bf16)v1.x; o[5] = (__bf16)v1.y; o[6] = (__bf16)v1.z; o[7] = (__bf16)v1.w;
    } else {
        #pragma unroll
        for (int j = 0; j < 8; ++j) o[j] = (__bf16)0.f;
    }
    *(bf16x8*)(xb + base) = o;
}

// ---- stage 0b: W [K][N] fp32 -> W^T [N][K] bf16 (tiled transpose) ----
__global__ void transpose_w_kernel(const float* __restrict__ W, __bf16* __restrict__ wT)
{
    __shared__ float tile[32][33];
    int nb = blockIdx.x * 32, kb = blockIdx.y * 32;
    int tx = threadIdx.x, ty = threadIdx.y;      // (32, 8)
    #pragma unroll
    for (int i = 0; i < 32; i += 8)
        tile[ty + i][tx] = W[(size_t)(kb + ty + i) * D_DIM + nb + tx];
    __syncthreads();
    #pragma unroll
    for (int i = 0; i < 32; i += 8)
        wT[(size_t)(nb + ty + i) * D_DIM + kb + tx] = (__bf16)tile[tx][ty + i];
}

// ---- stage 1: degree count over dst ----
__global__ __launch_bounds__(256) void count_kernel(
    const int* __restrict__ dst, int* __restrict__ cnt, int E)
{
    int e = blockIdx.x * 256 + threadIdx.x;
    if (e < E) atomicAdd(&cnt[dst[e]], 1);
}

// ---- stage 2: single-block scan (LDS-prefetched) -> row_ptr/cursor/dinv ----
// row_ptr is built from PADDED counts (ceil(cnt/8)*8) so the scatter inner
// loop runs exact 8-batches with zero remainder.
__global__ __launch_bounds__(1024) void scan_kernel(
    const int* __restrict__ cnt, int* __restrict__ row_ptr,
    int* __restrict__ cursor, float* __restrict__ dinv, int N)
{
    __shared__ int sbuf[10240];                  // N <= 10240
    __shared__ int wsum[16];
    __shared__ int sctot;
    int tid = threadIdx.x, lane = tid & 63, wid = tid >> 6;
    int chunks = (N + 1023) >> 10;
    #pragma unroll 4
    for (int ch = 0; ch < chunks; ++ch) {
        int i = (ch << 10) + tid;
        sbuf[(ch << 10) + tid] = (i < N) ? cnt[i] : 0;
    }
    __syncthreads();
    int carry = 0;
    for (int ch = 0; ch < chunks; ++ch) {
        int i = (ch << 10) + tid;
        int c = sbuf[(ch << 10) + tid];
        int p = (c + 7) & ~7;                    // padded degree
        int v = p;
        #pragma unroll
        for (int off = 1; off < 64; off <<= 1) {
            int t = __shfl_up(v, off);
            if (lane >= off) v += t;
        }
        if (lane == 63) wsum[wid] = v;
        __syncthreads();
        if (tid < 16) {
            int s = wsum[tid];
            int sv = s;
            #pragma unroll
            for (int off = 1; off < 16; off <<= 1) {
                int t = __shfl_up(sv, off);
                if (tid >= off) sv += t;
            }
            wsum[tid] = sv - s;                  // exclusive wave offset
            if (tid == 15) sctot = sv;
        }
        __syncthreads();
        int incl = carry + wsum[wid] + v;
        if (i < N) {
            int excl = incl - p;
            row_ptr[i] = excl;
            cursor[i]  = excl;
            dinv[i] = rsqrtf((float)c + 1.0f);   // +1 self loop, always > 0
        }
        carry += sctot;
        __syncthreads();
    }
    if (tid == 0) row_ptr[N] = carry;
}

// ---- stage 3: CSR fill (stores BYTE offsets src<<11 = src*2048) ----
__global__ __launch_bounds__(256) void fill_kernel(
    const int* __restrict__ src, const int* __restrict__ dst,
    int* __restrict__ cursor, int* __restrict__ col, int E)
{
    int e = blockIdx.x * 256 + threadIdx.x;
    if (e < E) {
        int d = dst[e];
        int pos = atomicAdd(&cursor[d], 1);
        col[pos] = src[e] << 11;
    }
}

// ---- stage 3b: pad rows to multiple of 8 with the zero row (index N) ----
// Rows N..MP-1 of h' are exactly zero (GEMM epilogue scales by dinv=0), so
// dummy edges contribute nothing. Requires N % 128 != 0 (true: N=10000).
__global__ __launch_bounds__(256) void pad_fill_kernel(
    const int* __restrict__ cursor, const int* __restrict__ row_ptr,
    int* __restrict__ col, int N)
{
    int d = blockIdx.x * 256 + threadIdx.x;
    if (d >= N) return;
    int zoff = N << 11;
    int p1 = row_ptr[d + 1];
    for (int p = cursor[d]; p < p1; ++p) col[p] = zoff;
}

// ---- stage 4: h' = (xb @ W) * dinv[row]  (pre-scaled by src norm) ----
// 128x128 tile, BK=64, XCD-chunked remap, 2-phase prefetch (double-buffered
// LDS, stage t+1 before compute t), T2 XOR-swizzle via inverse-swizzled
// GLOBAL source + linear LDS dest + swizzled ds_read.
__global__ __launch_bounds__(256) void gemm_kernel(
    const __bf16* __restrict__ A,   // [MP][K] bf16
    const __bf16* __restrict__ BT,  // [N][K] bf16 (W transposed)
    __bf16* __restrict__ C,         // [MP][N] bf16 (pre-scaled h')
    const float* __restrict__ dinv, int Nn,
    int K, int N, int mtiles, int ntiles, int chunk)
{
    __shared__ __bf16 As0[BM * BK], Bs0[BN * BK];
    __shared__ __bf16 As1[BM * BK], Bs1[BN * BK];

    int wg = blockIdx.x;
    int c8 = wg & (NXCD - 1);
    int r  = wg >> 3;
    int bm = c8 * chunk + r / ntiles;
    int bn = r % ntiles;
    if (bm >= mtiles) return;

    int tid = threadIdx.x;
    int wid = tid >> 6, lane = tid & 63;
    int wr = wid >> 1, wc = wid & 1;             // 2x2 wave grid, 64x64 each

    auto stage = [&](int ks, __bf16* dA, __bf16* dB) {
        #pragma unroll
        for (int i = 0; i < 4; ++i) {
            int c   = i * 256 + wid * 64 + lane; // 16B chunk id, lane-contiguous
            int row = c >> 3;                    // 8 chunks per 64-elem row
            int js  = (c & 7) ^ (row & 7);       // inverse-swizzled source chunk
            const __bf16* ga = A  + (size_t)(bm * BM + row) * K + ks * BK + js * 8;
            const __bf16* gb = BT + (size_t)(bn * BN + row) * K + ks * BK + js * 8;
            __builtin_amdgcn_global_load_lds(GLB(ga), LDS(dA + c * 8), 16, 0, 0);
            __builtin_amdgcn_global_load_lds(GLB(gb), LDS(dB + c * 8), 16, 0, 0);
        }
    };

    f32x4 acc[4][4] = {};
    const int ksteps = K / BK;

    __bf16 *rdA = As0, *rdB = Bs0, *wrA = As1, *wrB = Bs1;
    stage(0, rdA, rdB);
    asm volatile("s_waitcnt vmcnt(0)" ::: "memory");
    __syncthreads();

    for (int ks = 0; ks < ksteps; ++ks) {
        if (ks + 1 < ksteps) stage(ks + 1, wrA, wrB);   // prefetch next tile
        #pragma unroll
        for (int kk = 0; kk < 2; ++kk) {
            bf16x8 af[4], bfr[4];
            int jgrp = kk * 4 + (lane >> 4);             // chunk index 0..7
            #pragma unroll
            for (int mi = 0; mi < 4; ++mi) {
                int rr = wr * 64 + mi * 16 + (lane & 15);
                af[mi] = *(const bf16x8*)(rdA + rr * BK + ((jgrp ^ (rr & 7)) << 3));
            }
            #pragma unroll
            for (int ni = 0; ni < 4; ++ni) {
                int rr = wc * 64 + ni * 16 + (lane & 15);
                bfr[ni] = *(const bf16x8*)(rdB + rr * BK + ((jgrp ^ (rr & 7)) << 3));
            }
            #pragma unroll
            for (int mi = 0; mi < 4; ++mi)
                #pragma unroll
                for (int ni = 0; ni < 4; ++ni)
                    acc[mi][ni] = __builtin_amdgcn_mfma_f32_16x16x32_bf16(
                        af[mi], bfr[ni], acc[mi][ni], 0, 0, 0);
        }
        asm volatile("s_waitcnt vmcnt(0)" ::: "memory");  // prefetch landed
        __syncthreads();                                   // all waves done reading rd
        __bf16* t;
        t = rdA; rdA = wrA; wrA = t;
        t = rdB; rdB = wrB; wrB = t;
    }

    // C layout: col = lane&15, row = (lane>>4)*4 + r   [m89-verified]
    // Pre-scale by dinv[row]: h'[r] = h[r] * dinv[r]  (src-side GCN norm)
    #pragma unroll
    for (int mi = 0; mi < 4; ++mi)
        #pragma unroll
        for (int rr = 0; rr < 4; ++rr) {
            int row = bm * BM + wr * 64 + mi * 16 + (lane >> 4) * 4 + rr;
            float dvr = (row < Nn) ? dinv[row] : 0.0f;
            #pragma unroll
            for (int ni = 0; ni < 4; ++ni) {
                int colc = bn * BN + wc * 64 + ni * 16 + (lane & 15);
                C[(size_t)row * N + colc] = (__bf16)(acc[mi][ni][rr] * dvr);
            }
        }
}

// ---- stage 5: gather-accumulate + bias + ReLU, XCD-COLUMN-SLICED v3 ----
// Column chunk c = blockIdx%8 -> XCD c; per-XCD h' slice 2.6 MB < 4 MB L2
// (validated R7: FETCH 142->12.8 MB). v3: CSR rows padded to x8 (no
// remainder), col[] holds pre-shifted byte offsets (1 v_add addressing),
// f32x2 packed accumulate (v_pk_add_f32).
__global__ __launch_bounds__(256) void scatter_kernel(
    const __bf16* __restrict__ h, const int* __restrict__ row_ptr,
    const int* __restrict__ col, const float* __restrict__ dinv,
    const float* __restrict__ b, float* __restrict__ out, int N)
{
    int blk = blockIdx.x;
    int c   = blk & (NXCD - 1);                  // column chunk -> XCD
    int q   = blk >> 3;
    int wid = threadIdx.x >> 6, lane = threadIdx.x & 63;
    int d = q * 4 + wid;
    if (d >= N) return;

    const char* hb = (const char*)h + (size_t)c * 256;   // uniform base
    int lane4 = lane * 4;

    // self loop term (h' already has dinv[d] folded in)
    uint32_t su = *(const uint32_t*)(hb + (((uint32_t)d << 11) + lane4));
    f32x2 a;
    a[0] = __uint_as_float(su << 16);
    a[1] = __uint_as_float(su & 0xffff0000u);

    int r0 = row_ptr[d], r1 = row_ptr[d + 1];
    for (int e = r0; e < r1; e += 8) {
        int off[8];
        #pragma unroll
        for (int t = 0; t < 8; ++t) off[t] = col[e + t];
        uint32_t u[8];
        #pragma unroll
        for (int t = 0; t < 8; ++t)
            u[t] = *(const uint32_t*)(hb + ((uint32_t)off[t] + lane4));
        #pragma unroll
        for (int t = 0; t < 8; ++t) {
            f32x2 v;
            v[0] = __uint_as_float(u[t] << 16);
            v[1] = __uint_as_float(u[t] & 0xffff0000u);
            a += v;                               // v_pk_add_f32
        }
    }

    float dv = dinv[d];
    int cbase = c * 128 + lane * 2;
    f32x2 bb = *(const f32x2*)(b + cbase);
    f32x2 o;
    o[0] = fmaxf(fmaf(a[0], dv, bb[0]), 0.f);
    o[1] = fmaxf(fmaf(a[1], dv, bb[1]), 0.f);
    __builtin_nontemporal_store(o, (f32x2*)(out + (size_t)d * D_DIM + cbase));
}

extern "C" void kernel_launch(void* const* d_in, const int* in_sizes, int n_in,
                              void* d_out, int out_size, void* d_ws, size_t ws_size,
                              hipStream_t stream)
{
    const float* x  = (const float*)d_in[0];
    const int*   ei = (const int*)d_in[1];
    const float* W  = (const float*)d_in[2];
    const float* b  = (const float*)d_in[3];
    float* out = (float*)d_out;

    const int N = in_sizes[0] / D_DIM;     // 10000
    const int E = in_sizes[1] / 2;         // 160000
    const int MP = ((N + BM - 1) / BM) * BM; // 10112
    const int K = D_DIM;

    const int* src = ei;
    const int* dst = ei + E;

    // ws bump allocator, 256B aligned
    char* ws = (char*)d_ws;
    size_t off = 0;
    auto alloc = [&](size_t bytes) -> char* {
        char* p = ws + off;
        off += (bytes + 255) & ~(size_t)255;
        return p;
    };
    __bf16* xb     = (__bf16*)alloc((size_t)MP * D_DIM * 2);
    __bf16* wT     = (__bf16*)alloc((size_t)D_DIM * D_DIM * 2);
    __bf16* h      = (__bf16*)alloc((size_t)MP * D_DIM * 2);
    int*    cnt    = (int*)alloc((size_t)N * 4);
    int*    rowptr = (int*)alloc((size_t)(N + 1) * 4);
    int*    cursor = (int*)alloc((size_t)N * 4);
    int*    colbuf = (int*)alloc((size_t)(E + 7 * N + 64) * 4);
    float*  dinv   = (float*)alloc((size_t)N * 4);
    (void)ws_size;

    // 0: convert x -> padded bf16 (also zeroes cnt)
    int groups = MP * (D_DIM / 8);
    conv_x_kernel<<<(groups + 255) / 256, 256, 0, stream>>>(x, xb, cnt, N, MP);
    // 0b: W -> W^T bf16
    transpose_w_kernel<<<dim3(D_DIM / 32, D_DIM / 32), dim3(32, 8), 0, stream>>>(W, wT);
    // 1: degree count
    count_kernel<<<(E + 255) / 256, 256, 0, stream>>>(dst, cnt, E);
    // 2: scan (padded) -> row_ptr, cursor, dinv
    scan_kernel<<<1, 1024, 0, stream>>>(cnt, rowptr, cursor, dinv, N);
    // 3: CSR fill (byte offsets)
    fill_kernel<<<(E + 255) / 256, 256, 0, stream>>>(src, dst, cursor, colbuf, E);
    // 3b: pad rows to x8 with zero-row edges
    pad_fill_kernel<<<(N + 255) / 256, 256, 0, stream>>>(cursor, rowptr, colbuf, N);
    // 4: h' = (xb @ W) * dinv — XCD-chunked + 2-phase prefetch + swizzle
    int mtiles = MP / BM;                      // 79
    int ntiles = D_DIM / BN;                   // 8
    int chunk  = (mtiles + NXCD - 1) / NXCD;   // 10
    int nblocks = NXCD * chunk * ntiles;       // 640 (8 early-exit)
    gemm_kernel<<<nblocks, 256, 0, stream>>>(xb, wT, h, dinv, N, K, D_DIM,
                                             mtiles, ntiles, chunk);
    // 5: gather-accumulate + bias + relu — XCD column-sliced
    int sblocks = ((N + 3) / 4) * NXCD;        // 20000
    scatter_kernel<<<sblocks, 256, 0, stream>>>(h, rowptr, colbuf, dinv, b, out, N);
}

// Round 9
// 114.440 us; speedup vs baseline: 1.1354x; 1.0528x over previous
//
#include <hip/hip_runtime.h>
#include <hip/hip_bf16.h>
#include <cstdint>
#include <cstddef>

typedef __bf16 bf16x8 __attribute__((ext_vector_type(8)));
typedef float  f32x4  __attribute__((ext_vector_type(4)));
typedef float  f32x2  __attribute__((ext_vector_type(2)));

#define D_DIM 1024
#define BM 128
#define BN 128
#define BK 64
#define NXCD 8

#define GLB(p) ((const __attribute__((address_space(1))) void*)(p))
#define LDS(p) ((__attribute__((address_space(3))) void*)(p))

// ---- stage 0 (fused): conv x->bf16 (padded) + W transpose->bf16 + zero cnt ----
__global__ __launch_bounds__(256) void prep_kernel(
    const float* __restrict__ x, __bf16* __restrict__ xb,
    const float* __restrict__ W, __bf16* __restrict__ wT,
    int* __restrict__ cnt, int N, int MP, int nconv)
{
    int blk = blockIdx.x, tid = threadIdx.x;
    if (blk < nconv) {
        int i = blk * 256 + tid;                 // group of 8 elements
        if (i < N) cnt[i] = 0;                   // zero degree counters
        int total = MP * (D_DIM / 8);
        if (i >= total) return;
        int row = i >> 7;                        // D/8 = 128 groups per row
        size_t base = (size_t)i * 8;
        bf16x8 o;
        if (row < N) {
            float4 v0 = *(const float4*)(x + base);
            float4 v1 = *(const float4*)(x + base + 4);
            o[0] = (__bf16)v0.x; o[1] = (__bf16)v0.y; o[2] = (__bf16)v0.z; o[3] = (__bf16)v0.w;
            o[4] = (__bf16)v1.x; o[5] = (__bf16)v1.y; o[6] = (__bf16)v1.z; o[7] = (__bf16)v1.w;
        } else {
            #pragma unroll
            for (int j = 0; j < 8; ++j) o[j] = (__bf16)0.f;
        }
        *(bf16x8*)(xb + base) = o;
    } else {
        // W [K][N] fp32 -> W^T [N][K] bf16, 32x32 tile per block
        __shared__ float tile[32][33];
        int bb = blk - nconv;
        int nb = (bb & 31) * 32, kb = (bb >> 5) * 32;
        int tx = tid & 31, ty = tid >> 5;        // (32, 8)
        #pragma unroll
        for (int i = 0; i < 32; i += 8)
            tile[ty + i][tx] = W[(size_t)(kb + ty + i) * D_DIM + nb + tx];
        __syncthreads();
        #pragma unroll
        for (int i = 0; i < 32; i += 8)
            wT[(size_t)(nb + ty + i) * D_DIM + kb + tx] = (__bf16)tile[tx][ty + i];
    }
}

// ---- stage 1: degree count over dst ----
__global__ __launch_bounds__(256) void count_kernel(
    const int* __restrict__ dst, int* __restrict__ cnt, int E)
{
    int e = blockIdx.x * 256 + threadIdx.x;
    if (e < E) atomicAdd(&cnt[dst[e]], 1);
}

// ---- stage 2: single-block scan (LDS-prefetched) -> row_ptr/cursor/dinv ----
// row_ptr is built from PADDED counts (ceil(cnt/8)*8) so the scatter inner
// loop runs exact 8-batches with zero remainder.
__global__ __launch_bounds__(1024) void scan_kernel(
    const int* __restrict__ cnt, int* __restrict__ row_ptr,
    int* __restrict__ cursor, float* __restrict__ dinv, int N)
{
    __shared__ int sbuf[10240];                  // N <= 10240
    __shared__ int wsum[16];
    __shared__ int sctot;
    int tid = threadIdx.x, lane = tid & 63, wid = tid >> 6;
    int chunks = (N + 1023) >> 10;
    #pragma unroll 4
    for (int ch = 0; ch < chunks; ++ch) {
        int i = (ch << 10) + tid;
        sbuf[(ch << 10) + tid] = (i < N) ? cnt[i] : 0;
    }
    __syncthreads();
    int carry = 0;
    for (int ch = 0; ch < chunks; ++ch) {
        int i = (ch << 10) + tid;
        int c = sbuf[(ch << 10) + tid];
        int p = (c + 7) & ~7;                    // padded degree
        int v = p;
        #pragma unroll
        for (int off = 1; off < 64; off <<= 1) {
            int t = __shfl_up(v, off);
            if (lane >= off) v += t;
        }
        if (lane == 63) wsum[wid] = v;
        __syncthreads();
        if (tid < 16) {
            int s = wsum[tid];
            int sv = s;
            #pragma unroll
            for (int off = 1; off < 16; off <<= 1) {
                int t = __shfl_up(sv, off);
                if (tid >= off) sv += t;
            }
            wsum[tid] = sv - s;                  // exclusive wave offset
            if (tid == 15) sctot = sv;
        }
        __syncthreads();
        int incl = carry + wsum[wid] + v;
        if (i < N) {
            int excl = incl - p;
            row_ptr[i] = excl;
            cursor[i]  = excl;
            dinv[i] = rsqrtf((float)c + 1.0f);   // +1 self loop, always > 0
        }
        carry += sctot;
        __syncthreads();
    }
    if (tid == 0) row_ptr[N] = carry;
}

// ---- stage 3 (fused): CSR fill (byte offsets src<<11) + pad-to-x8 ----
// Pad region [row_ptr[d]+cnt[d], row_ptr[d+1]) is disjoint from fill's
// cursor range [row_ptr[d], row_ptr[d]+cnt[d]) -> safe to co-run.
__global__ __launch_bounds__(256) void fillpad_kernel(
    const int* __restrict__ src, const int* __restrict__ dst,
    int* __restrict__ cursor, const int* __restrict__ cnt,
    const int* __restrict__ row_ptr, int* __restrict__ col,
    int E, int N, int nfill)
{
    int blk = blockIdx.x, tid = threadIdx.x;
    if (blk < nfill) {
        int e = blk * 256 + tid;
        if (e < E) {
            int d = dst[e];
            int pos = atomicAdd(&cursor[d], 1);
            col[pos] = src[e] << 11;
        }
    } else {
        int d = (blk - nfill) * 256 + tid;
        if (d >= N) return;
        int zoff = N << 11;                      // zero row (h'[N]==0)
        int p1 = row_ptr[d + 1];
        for (int p = row_ptr[d] + cnt[d]; p < p1; ++p) col[p] = zoff;
    }
}

// ---- stage 4: h' = (xb @ W) * dinv[row] ----
// m97 structure: SINGLE-buffer 32 KB LDS (5 blocks/CU capacity -> all 632
// tiles co-resident, no occupancy tail; R3's 64KB dbuf capped at 2/CU),
// 2 barriers per K-step, T2 swizzle via inverse-swizzled global source +
// linear LDS dest + swizzled ds_read; XCD-chunked block remap.
__global__ __launch_bounds__(256) void gemm_kernel(
    const __bf16* __restrict__ A,   // [MP][K] bf16
    const __bf16* __restrict__ BT,  // [N][K] bf16 (W transposed)
    __bf16* __restrict__ C,         // [MP][N] bf16 (pre-scaled h')
    const float* __restrict__ dinv, int Nn,
    int K, int N, int mtiles, int ntiles, int chunk)
{
    __shared__ __bf16 As[BM * BK];
    __shared__ __bf16 Bs[BN * BK];

    int wg = blockIdx.x;
    int c8 = wg & (NXCD - 1);
    int r  = wg >> 3;
    int bm = c8 * chunk + r / ntiles;
    int bn = r % ntiles;
    if (bm >= mtiles) return;

    int tid = threadIdx.x;
    int wid = tid >> 6, lane = tid & 63;
    int wr = wid >> 1, wc = wid & 1;             // 2x2 wave grid, 64x64 each

    f32x4 acc[4][4] = {};
    const int ksteps = K / BK;

    for (int ks = 0; ks < ksteps; ++ks) {
        #pragma unroll
        for (int i = 0; i < 4; ++i) {
            int c   = i * 256 + wid * 64 + lane; // 16B chunk id, lane-contiguous
            int row = c >> 3;                    // 8 chunks per 64-elem row
            int js  = (c & 7) ^ (row & 7);       // inverse-swizzled source chunk
            const __bf16* ga = A  + (size_t)(bm * BM + row) * K + ks * BK + js * 8;
            const __bf16* gb = BT + (size_t)(bn * BN + row) * K + ks * BK + js * 8;
            __builtin_amdgcn_global_load_lds(GLB(ga), LDS(As + c * 8), 16, 0, 0);
            __builtin_amdgcn_global_load_lds(GLB(gb), LDS(Bs + c * 8), 16, 0, 0);
        }
        asm volatile("s_waitcnt vmcnt(0)" ::: "memory");
        __syncthreads();
        #pragma unroll
        for (int kk = 0; kk < 2; ++kk) {
            bf16x8 af[4], bfr[4];
            int jgrp = kk * 4 + (lane >> 4);     // chunk index 0..7
            #pragma unroll
            for (int mi = 0; mi < 4; ++mi) {
                int rr = wr * 64 + mi * 16 + (lane & 15);
                af[mi] = *(const bf16x8*)(As + rr * BK + ((jgrp ^ (rr & 7)) << 3));
            }
            #pragma unroll
            for (int ni = 0; ni < 4; ++ni) {
                int rr = wc * 64 + ni * 16 + (lane & 15);
                bfr[ni] = *(const bf16x8*)(Bs + rr * BK + ((jgrp ^ (rr & 7)) << 3));
            }
            #pragma unroll
            for (int mi = 0; mi < 4; ++mi)
                #pragma unroll
                for (int ni = 0; ni < 4; ++ni)
                    acc[mi][ni] = __builtin_amdgcn_mfma_f32_16x16x32_bf16(
                        af[mi], bfr[ni], acc[mi][ni], 0, 0, 0);
        }
        __syncthreads();                          // all waves done reading LDS
    }

    // C layout: col = lane&15, row = (lane>>4)*4 + r   [m89-verified]
    // Pre-scale by dinv[row]: h'[r] = h[r] * dinv[r]  (src-side GCN norm)
    #pragma unroll
    for (int mi = 0; mi < 4; ++mi)
        #pragma unroll
        for (int rr = 0; rr < 4; ++rr) {
            int row = bm * BM + wr * 64 + mi * 16 + (lane >> 4) * 4 + rr;
            float dvr = (row < Nn) ? dinv[row] : 0.0f;
            #pragma unroll
            for (int ni = 0; ni < 4; ++ni) {
                int colc = bn * BN + wc * 64 + ni * 16 + (lane & 15);
                C[(size_t)row * N + colc] = (__bf16)(acc[mi][ni][rr] * dvr);
            }
        }
}

// ---- stage 5: gather-accumulate + bias + ReLU, XCD-COLUMN-SLICED v4 ----
// Column chunk c = blockIdx%8 -> XCD c; per-XCD h' slice 2.6 MB < 4 MB L2
// (validated R7: FETCH 142->12.8 MB). v4: col batch loads as 2x int4
// (e 8-aligned by padding -> 32B aligned), byte-offset addressing,
// f32x2 packed accumulate.
__global__ __launch_bounds__(256) void scatter_kernel(
    const __bf16* __restrict__ h, const int* __restrict__ row_ptr,
    const int* __restrict__ col, const float* __restrict__ dinv,
    const float* __restrict__ b, float* __restrict__ out, int N)
{
    int blk = blockIdx.x;
    int c   = blk & (NXCD - 1);                  // column chunk -> XCD
    int q   = blk >> 3;
    int wid = threadIdx.x >> 6, lane = threadIdx.x & 63;
    int d = q * 4 + wid;
    if (d >= N) return;

    const char* hb = (const char*)h + (size_t)c * 256;   // uniform base
    int lane4 = lane * 4;

    // self loop term (h' already has dinv[d] folded in)
    uint32_t su = *(const uint32_t*)(hb + (((uint32_t)d << 11) + lane4));
    f32x2 a;
    a[0] = __uint_as_float(su << 16);
    a[1] = __uint_as_float(su & 0xffff0000u);

    int r0 = row_ptr[d], r1 = row_ptr[d + 1];
    for (int e = r0; e < r1; e += 8) {
        int4 c0 = *(const int4*)(col + e);
        int4 c1 = *(const int4*)(col + e + 4);
        uint32_t u[8];
        u[0] = *(const uint32_t*)(hb + ((uint32_t)c0.x + lane4));
        u[1] = *(const uint32_t*)(hb + ((uint32_t)c0.y + lane4));
        u[2] = *(const uint32_t*)(hb + ((uint32_t)c0.z + lane4));
        u[3] = *(const uint32_t*)(hb + ((uint32_t)c0.w + lane4));
        u[4] = *(const uint32_t*)(hb + ((uint32_t)c1.x + lane4));
        u[5] = *(const uint32_t*)(hb + ((uint32_t)c1.y + lane4));
        u[6] = *(const uint32_t*)(hb + ((uint32_t)c1.z + lane4));
        u[7] = *(const uint32_t*)(hb + ((uint32_t)c1.w + lane4));
        #pragma unroll
        for (int t = 0; t < 8; ++t) {
            f32x2 v;
            v[0] = __uint_as_float(u[t] << 16);
            v[1] = __uint_as_float(u[t] & 0xffff0000u);
            a += v;                               // v_pk_add_f32
        }
    }

    float dv = dinv[d];
    int cbase = c * 128 + lane * 2;
    f32x2 bb = *(const f32x2*)(b + cbase);
    f32x2 o;
    o[0] = fmaxf(fmaf(a[0], dv, bb[0]), 0.f);
    o[1] = fmaxf(fmaf(a[1], dv, bb[1]), 0.f);
    __builtin_nontemporal_store(o, (f32x2*)(out + (size_t)d * D_DIM + cbase));
}

extern "C" void kernel_launch(void* const* d_in, const int* in_sizes, int n_in,
                              void* d_out, int out_size, void* d_ws, size_t ws_size,
                              hipStream_t stream)
{
    const float* x  = (const float*)d_in[0];
    const int*   ei = (const int*)d_in[1];
    const float* W  = (const float*)d_in[2];
    const float* b  = (const float*)d_in[3];
    float* out = (float*)d_out;

    const int N = in_sizes[0] / D_DIM;     // 10000
    const int E = in_sizes[1] / 2;         // 160000
    const int MP = ((N + BM - 1) / BM) * BM; // 10112
    const int K = D_DIM;

    const int* src = ei;
    const int* dst = ei + E;

    // ws bump allocator, 256B aligned
    char* ws = (char*)d_ws;
    size_t off = 0;
    auto alloc = [&](size_t bytes) -> char* {
        char* p = ws + off;
        off += (bytes + 255) & ~(size_t)255;
        return p;
    };
    __bf16* xb     = (__bf16*)alloc((size_t)MP * D_DIM * 2);
    __bf16* wT     = (__bf16*)alloc((size_t)D_DIM * D_DIM * 2);
    __bf16* h      = (__bf16*)alloc((size_t)MP * D_DIM * 2);
    int*    cnt    = (int*)alloc((size_t)N * 4);
    int*    rowptr = (int*)alloc((size_t)(N + 1) * 4);
    int*    cursor = (int*)alloc((size_t)N * 4);
    int*    colbuf = (int*)alloc((size_t)(E + 7 * N + 64) * 4);
    float*  dinv   = (float*)alloc((size_t)N * 4);
    (void)ws_size;

    // 0: fused conv_x + W^T + cnt zero
    int nconv = (MP * (D_DIM / 8) + 255) / 256;          // 5056
    int ntr   = (D_DIM / 32) * (D_DIM / 32);             // 1024
    prep_kernel<<<nconv + ntr, 256, 0, stream>>>(x, xb, W, wT, cnt, N, MP, nconv);
    // 1: degree count
    count_kernel<<<(E + 255) / 256, 256, 0, stream>>>(dst, cnt, E);
    // 2: scan (padded) -> row_ptr, cursor, dinv
    scan_kernel<<<1, 1024, 0, stream>>>(cnt, rowptr, cursor, dinv, N);
    // 3: fused CSR fill + pad
    int nfill = (E + 255) / 256;                         // 625
    int npad  = (N + 255) / 256;                         // 40
    fillpad_kernel<<<nfill + npad, 256, 0, stream>>>(src, dst, cursor, cnt,
                                                     rowptr, colbuf, E, N, nfill);
    // 4: h' = (xb @ W) * dinv — single-buffer m97 structure + swizzle + XCD chunk
    int mtiles = MP / BM;                      // 79
    int ntiles = D_DIM / BN;                   // 8
    int chunk  = (mtiles + NXCD - 1) / NXCD;   // 10
    int nblocks = NXCD * chunk * ntiles;       // 640 (8 early-exit)
    gemm_kernel<<<nblocks, 256, 0, stream>>>(xb, wT, h, dinv, N, K, D_DIM,
                                             mtiles, ntiles, chunk);
    // 5: gather-accumulate + bias + relu — XCD column-sliced
    int sblocks = ((N + 3) / 4) * NXCD;        // 20000
    scatter_kernel<<<sblocks, 256, 0, stream>>>(h, rowptr, colbuf, dinv, b, out, N);
}